// Round 16
// baseline (217.171 us; speedup 1.0000x reference)
//
#include <hip/hip_runtime.h>
#include <hip/hip_bf16.h>

#define BN 16
#define SN 2048
#define DM 512
#define HN 8
#define PN 128
#define DEPTH 64
#define CSZ 16

typedef unsigned short u16;
typedef __bf16 bf16x8 __attribute__((ext_vector_type(8)));
typedef float f32x4 __attribute__((ext_vector_type(4)));

// workspace layout (float-unit offsets)
#define OFF_QB   0ull          // Q bf16 (16.7M u16)
#define OFF_G    8388608ull    // G bf16: [(kv*8+h)*16+b][128 p][512] = 32768x512 u16
#define OFF_CB   25165824ull   // concat bf16
#define OFF_WQT  33554432ull   // 4x(512x512) u16 transposed (wq,wk,wv,dw)
#define OFF_WKT  33685504ull
#define OFF_WVT  33816576ull
#define OFF_DWT  33947648ull
#define OFF_KP   34078720ull   // (unused since R16 — kept for layout stability)
#define OFF_VPT  35127296ull   // u16 [bh][d=64][p=128]
#define OFF_KEP  35651584ull   // u16 [bh][p=128][320]
#define OFF_EFF  38273024ull
#define OFF_CNT  38273664ull
#define OFF_XB   38273792ull   // x bf16 (16.7M u16)

__device__ __forceinline__ u16 f2bf(float f) {
    unsigned u = __float_as_uint(f);
    u = (u + 0x7fffu + ((u >> 16) & 1u)) >> 16;   // RNE
    return (u16)u;
}
__device__ __forceinline__ float b2f(u16 h) {
    return __uint_as_float(((unsigned)h) << 16);
}

// chunked XCD swizzle: consecutive dispatch ids round-robin the 8 XCDs.
__device__ __forceinline__ void xcd_decode(int bid, int nmem, int& g, int& j) {
    int xcd = bid & 7;
    int t = bid >> 3;
    j = t % nmem;
    g = (t / nmem) * 8 + xcd;
}

// ---------------- prep: counts (blocks 0..15) + eff conv combine (block 16) ----------------
__global__ void prep_kernel(const void* mask, int* counts,
                            const float* ck1, const float* ck3, const float* ck5, float* eff) {
    int tid = threadIdx.x;
    if (blockIdx.x == 16) {
        for (int i = tid; i < 640; i += 256) {
            int t = i >> 7, j = i & 127;
            float v = ck5[t * 128 + j];
            if (t >= 1 && t <= 3) v += ck3[(t - 1) * 128 + j];
            if (t == 2) v += ck1[j];
            eff[i] = v * (1.0f / 3.0f);
        }
        return;
    }
    __shared__ int red[256];
    int b = blockIdx.x;
    const unsigned char* mb = (const unsigned char*)mask;
    bool is_byte = (mb[1] != 0);  // byte1 nonzero iff 1-byte bool storage (len>=1024)
    int local = 0;
    if (is_byte) {
        const unsigned char* row = mb + (size_t)b * SN;
        for (int s = tid; s < SN; s += 256) local += (row[s] != 0);
    } else {
        const int* row = (const int*)mask + (size_t)b * SN;
        for (int s = tid; s < SN; s += 256) local += (row[s] != 0);
    }
    red[tid] = local;
    __syncthreads();
    for (int st = 128; st > 0; st >>= 1) {
        if (tid < st) red[tid] += red[tid + st];
        __syncthreads();
    }
    if (tid == 0) {
        int c = red[0];
        if (c < 1) c = 1;
        if (c > SN) c = SN;
        counts[b] = c;
    }
}

// ---------------- f32 -> bf16 convert (x): 16 floats/thread, 4096 blocks ----------------
__global__ __launch_bounds__(256) void convert_x_kernel(const float* __restrict__ x, u16* __restrict__ xb) {
    size_t i = ((size_t)blockIdx.x * 256 + threadIdx.x) * 16;
#pragma unroll
    for (int k = 0; k < 4; k++) {
        float4 v = *(const float4*)&x[i + k * 4];
        ushort4 o;
        o.x = f2bf(v.x); o.y = f2bf(v.y); o.z = f2bf(v.z); o.w = f2bf(v.w);
        *(ushort4*)&xb[i + k * 4] = o;
    }
}

// ---------------- weight transpose+convert: Wt[n][k] = bf16(W[k][n]) ----------------
__global__ void convert_wT_kernel(const float* w0, const float* w1, const float* w2, const float* w3,
                                  u16* o0, u16* o1, u16* o2, u16* o3) {
    int z = blockIdx.z;
    const float* W = (z == 0) ? w0 : (z == 1) ? w1 : (z == 2) ? w2 : w3;
    u16* O = (z == 0) ? o0 : (z == 1) ? o1 : (z == 2) ? o2 : o3;
    __shared__ float t[32][33];
    int k0 = blockIdx.y * 32, n0 = blockIdx.x * 32;
    int lx = threadIdx.x & 31, ly = threadIdx.x >> 5;  // 32 x 8
#pragma unroll
    for (int i = 0; i < 4; i++) t[ly + i * 8][lx] = W[(size_t)(k0 + ly + i * 8) * 512 + n0 + lx];
    __syncthreads();
#pragma unroll
    for (int i = 0; i < 4; i++) O[(size_t)(n0 + ly + i * 8) * 512 + k0 + lx] = f2bf(t[lx][ly + i * 8]);
}

// ---------------- Q GEMM: xb(32768x512)bf16 @ wqT -> Q bf16 (B,H,S,depth) scatter ----------------
__global__ __launch_bounds__(256) void gemm_q(const u16* __restrict__ A,
                                              const u16* __restrict__ WT,
                                              u16* __restrict__ Q) {
    __shared__ __align__(16) char smem[32768];
    char* AsB = smem;
    char* BsB = smem + 16384;

    int g, j;
    xcd_decode(blockIdx.x, 4, g, j);   // 256 m-groups x 4 n-members
    const int m0 = g * 128, n0 = j * 128;
    const int tid = threadIdx.x;
    const int w = tid >> 6, l = tid & 63;
    const int wm = w >> 1, wn = w & 1;
    const int lr = l >> 3, sp = l & 7;
    const int slog = sp ^ lr;
    const int cl = l & 15, kg = l >> 4;

    const char* Ab = (const char*)A;
    const char* Bb = (const char*)WT;

    f32x4 acc[4][4];
    const f32x4 z4 = {0.f, 0.f, 0.f, 0.f};
#pragma unroll
    for (int mf = 0; mf < 4; mf++)
#pragma unroll
        for (int nf = 0; nf < 4; nf++) acc[mf][nf] = z4;

    for (int kt = 0; kt < 8; kt++) {
        __syncthreads();
#pragma unroll
        for (int i = 0; i < 4; i++) {
            int c = w * 4 + i;
            const char* ga = Ab + (size_t)(m0 + c * 8 + lr) * 1024 + kt * 128 + slog * 16;
            __builtin_amdgcn_global_load_lds((const __attribute__((address_space(1))) void*)ga,
                                             (__attribute__((address_space(3))) void*)(AsB + c * 1024),
                                             16, 0, 0);
            const char* gb = Bb + (size_t)(n0 + c * 8 + lr) * 1024 + kt * 128 + slog * 16;
            __builtin_amdgcn_global_load_lds((const __attribute__((address_space(1))) void*)gb,
                                             (__attribute__((address_space(3))) void*)(BsB + c * 1024),
                                             16, 0, 0);
        }
        __syncthreads();
#pragma unroll
        for (int ks = 0; ks < 2; ks++) {
            bf16x8 a[4], b[4];
#pragma unroll
            for (int mf = 0; mf < 4; mf++) {
                int row = wm * 64 + mf * 16 + cl;
                a[mf] = *(const bf16x8*)(AsB + row * 128 + (((ks * 4 + kg) ^ (row & 7)) * 16));
            }
#pragma unroll
            for (int nf = 0; nf < 4; nf++) {
                int row = wn * 64 + nf * 16 + cl;
                b[nf] = *(const bf16x8*)(BsB + row * 128 + (((ks * 4 + kg) ^ (row & 7)) * 16));
            }
#pragma unroll
            for (int mf = 0; mf < 4; mf++)
#pragma unroll
                for (int nf = 0; nf < 4; nf++)
                    acc[mf][nf] = __builtin_amdgcn_mfma_f32_16x16x32_bf16(a[mf], b[nf], acc[mf][nf], 0, 0, 0);
        }
    }

    const int rl = l >> 4;
#pragma unroll
    for (int mf = 0; mf < 4; mf++)
#pragma unroll
        for (int nf = 0; nf < 4; nf++) {
            f32x4 v = acc[mf][nf];
            int n = n0 + wn * 64 + nf * 16 + cl;
            int h = n >> 6, d = n & 63;
#pragma unroll
            for (int r = 0; r < 4; r++) {
                int m = m0 + wm * 64 + mf * 16 + rl * 4 + r;
                int b = m >> 11, s = m & 2047;
                Q[(size_t)((b * HN + h) * SN + s) * DEPTH + d] = f2bf(v[r]);
            }
        }
}

// ---------------- output projection GEMM: cb(32768x512)bf16 @ dwT + bias -> f32 ----------------
__global__ __launch_bounds__(256) void gemm_out(const u16* __restrict__ A,
                                                const u16* __restrict__ WT,
                                                float* __restrict__ O,
                                                const float* __restrict__ bias) {
    __shared__ __align__(16) char smem[32768];
    char* AsB = smem;
    char* BsB = smem + 16384;

    int g, j;
    xcd_decode(blockIdx.x, 4, g, j);   // 256 m-groups x 4 n-members
    const int m0 = g * 128, n0 = j * 128;
    const int tid = threadIdx.x;
    const int w = tid >> 6, l = tid & 63;
    const int wm = w >> 1, wn = w & 1;
    const int lr = l >> 3, sp = l & 7;
    const int slog = sp ^ lr;
    const int cl = l & 15, kg = l >> 4;

    const char* Ab = (const char*)A;
    const char* Bb = (const char*)WT;

    f32x4 acc[4][4];
    const f32x4 z4 = {0.f, 0.f, 0.f, 0.f};
#pragma unroll
    for (int mf = 0; mf < 4; mf++)
#pragma unroll
        for (int nf = 0; nf < 4; nf++) acc[mf][nf] = z4;

    for (int kt = 0; kt < 8; kt++) {
        __syncthreads();
#pragma unroll
        for (int i = 0; i < 4; i++) {
            int c = w * 4 + i;
            const char* ga = Ab + (size_t)(m0 + c * 8 + lr) * 1024 + kt * 128 + slog * 16;
            __builtin_amdgcn_global_load_lds((const __attribute__((address_space(1))) void*)ga,
                                             (__attribute__((address_space(3))) void*)(AsB + c * 1024),
                                             16, 0, 0);
            const char* gb = Bb + (size_t)(n0 + c * 8 + lr) * 1024 + kt * 128 + slog * 16;
            __builtin_amdgcn_global_load_lds((const __attribute__((address_space(1))) void*)gb,
                                             (__attribute__((address_space(3))) void*)(BsB + c * 1024),
                                             16, 0, 0);
        }
        __syncthreads();
#pragma unroll
        for (int ks = 0; ks < 2; ks++) {
            bf16x8 a[4], b[4];
#pragma unroll
            for (int mf = 0; mf < 4; mf++) {
                int row = wm * 64 + mf * 16 + cl;
                a[mf] = *(const bf16x8*)(AsB + row * 128 + (((ks * 4 + kg) ^ (row & 7)) * 16));
            }
#pragma unroll
            for (int nf = 0; nf < 4; nf++) {
                int row = wn * 64 + nf * 16 + cl;
                b[nf] = *(const bf16x8*)(BsB + row * 128 + (((ks * 4 + kg) ^ (row & 7)) * 16));
            }
#pragma unroll
            for (int mf = 0; mf < 4; mf++)
#pragma unroll
                for (int nf = 0; nf < 4; nf++)
                    acc[mf][nf] = __builtin_amdgcn_mfma_f32_16x16x32_bf16(a[mf], b[nf], acc[mf][nf], 0, 0, 0);
        }
    }

    const int rl = l >> 4;
#pragma unroll
    for (int mf = 0; mf < 4; mf++)
#pragma unroll
        for (int nf = 0; nf < 4; nf++) {
            f32x4 v = acc[mf][nf];
            int n = n0 + wn * 64 + nf * 16 + cl;
            float bs = bias[n];
#pragma unroll
            for (int r = 0; r < 4; r++) {
                int m = m0 + wm * 64 + mf * 16 + rl * 4 + r;
                O[(size_t)m * 512 + n] = v[r] + bs;
            }
        }
}

// ---------------- gather+combine: G[(kv*8+h)*16+b][p][dm] = bf16(Sum_c w[h][p][c] * xb[b][pos][dm]) ----------------
__global__ __launch_bounds__(256) void gather_kernel(const u16* __restrict__ xb,
                                                     const int* __restrict__ table, const int* __restrict__ counts,
                                                     const float* __restrict__ e_w, const float* __restrict__ f_w,
                                                     u16* __restrict__ G) {
    int p = blockIdx.x;   // 0..127
    int b = blockIdx.y;   // 0..15
    int tid = threadIdx.x;
    __shared__ int poss[16];
    __shared__ float ew_s[8][16], fw_s[8][16];
    if (tid < 16) {
        int R = counts[b];
        poss[tid] = table[(size_t)(R - 1) * PN * CSZ + p * CSZ + tid];
    }
    {
        int t2 = tid & 127;
        int h = t2 >> 4, c = t2 & 15;
        float v = ((tid < 128) ? e_w : f_w)[(size_t)(h * PN + p) * CSZ + c];
        if (tid < 128) ew_s[h][c] = v; else fw_s[h][c] = v;
    }
    __syncthreads();

    const u16* xrow = xb + (size_t)b * SN * 512;
#pragma unroll
    for (int half = 0; half < 2; half++) {
        int dm = half * 256 + tid;
        float ak[8] = {0.f, 0.f, 0.f, 0.f, 0.f, 0.f, 0.f, 0.f};
        float av[8] = {0.f, 0.f, 0.f, 0.f, 0.f, 0.f, 0.f, 0.f};
#pragma unroll
        for (int c = 0; c < 16; c++) {
            int pos = poss[c];
            if (pos < SN) {
                float xv = b2f(xrow[(size_t)pos * 512 + dm]);
#pragma unroll
                for (int h = 0; h < 8; h++) {
                    ak[h] = fmaf(ew_s[h][c], xv, ak[h]);
                    av[h] = fmaf(fw_s[h][c], xv, av[h]);
                }
            }
        }
#pragma unroll
        for (int h = 0; h < 8; h++) {
            G[((size_t)(h * 16 + b) * 128 + p) * 512 + dm] = f2bf(ak[h]);
            G[((size_t)((8 + h) * 16 + b) * 128 + p) * 512 + dm] = f2bf(av[h]);
        }
    }
}

// ---------------- proj+ke fused: per (kv,h,b) tile G[128x512] @ w{k,v}T[h-slice 64x512] ----------------
// kv=1 -> vpT bf16 (as before). kv=0 (R16): kp tile stays ON-CHIP — scatter acc into
// zero-padded LDS kpad[256][36] (overlaying dead staging; stride 36 = best float4-
// aligned banking) and run the R1 conv fold twice (d-halves), writing keP directly.
// Saves ke_kernel launch + 8MB kp round-trip; arithmetic bit-identical.
__global__ __launch_bounds__(256) void proj_kernel(const u16* __restrict__ G,
                                                   const u16* __restrict__ wkT, const u16* __restrict__ wvT,
                                                   const float* __restrict__ eff,
                                                   u16* __restrict__ keP, u16* __restrict__ vpT) {
    __shared__ __align__(16) char smem[39424];
    char* AsB = smem;           // staging: 128 rows x 64k bf16 = 16KB
    char* BsB = smem + 16384;   // staging: 64 rows x 64k bf16 = 8KB
    float* kpad = (float*)smem;            // conv phase: [256 rows][36] f32 (overlays staging)
    float* ef = (float*)(smem + 36864);    // 640 f32 (beyond staging region)

    const int mt = blockIdx.x;          // 0..255 = kv*128 + h*16 + b
    const int kv = mt >> 7, h = (mt >> 4) & 7, bb = mt & 15;
    const int tid = threadIdx.x;
    const int w = tid >> 6, l = tid & 63;
    const int wm = w >> 1, wn = w & 1;
    const int lr = l >> 3, sp = l & 7;
    const int slog = sp ^ lr;
    const int cl = l & 15, kg = l >> 4;

    const char* Ab = (const char*)(G + (size_t)mt * 65536);
    const char* Bb = (const char*)((kv ? wvT : wkT) + (size_t)h * 64 * 512);

    f32x4 acc[4][2];
    const f32x4 z4 = {0.f, 0.f, 0.f, 0.f};
#pragma unroll
    for (int mf = 0; mf < 4; mf++)
#pragma unroll
        for (int nf = 0; nf < 2; nf++) acc[mf][nf] = z4;

    for (int kt = 0; kt < 8; kt++) {
        __syncthreads();
#pragma unroll
        for (int i = 0; i < 4; i++) {
            int c = w * 4 + i;
            const char* ga = Ab + (size_t)(c * 8 + lr) * 1024 + kt * 128 + slog * 16;
            __builtin_amdgcn_global_load_lds((const __attribute__((address_space(1))) void*)ga,
                                             (__attribute__((address_space(3))) void*)(AsB + c * 1024),
                                             16, 0, 0);
        }
#pragma unroll
        for (int i = 0; i < 2; i++) {
            int c = w * 2 + i;
            const char* gb = Bb + (size_t)(c * 8 + lr) * 1024 + kt * 128 + slog * 16;
            __builtin_amdgcn_global_load_lds((const __attribute__((address_space(1))) void*)gb,
                                             (__attribute__((address_space(3))) void*)(BsB + c * 1024),
                                             16, 0, 0);
        }
        __syncthreads();
#pragma unroll
        for (int ks = 0; ks < 2; ks++) {
            bf16x8 a[4], b[2];
#pragma unroll
            for (int mf = 0; mf < 4; mf++) {
                int row = wm * 64 + mf * 16 + cl;
                a[mf] = *(const bf16x8*)(AsB + row * 128 + (((ks * 4 + kg) ^ (row & 7)) * 16));
            }
#pragma unroll
            for (int nf = 0; nf < 2; nf++) {
                int row = wn * 32 + nf * 16 + cl;
                b[nf] = *(const bf16x8*)(BsB + row * 128 + (((ks * 4 + kg) ^ (row & 7)) * 16));
            }
#pragma unroll
            for (int mf = 0; mf < 4; mf++)
#pragma unroll
                for (int nf = 0; nf < 2; nf++)
                    acc[mf][nf] = __builtin_amdgcn_mfma_f32_16x16x32_bf16(a[mf], b[nf], acc[mf][nf], 0, 0, 0);
        }
    }

    const int rl = l >> 4;
    const int bh = bb * HN + h;

    if (kv == 1) {
        // V path: write transposed bf16 (unchanged)
#pragma unroll
        for (int mf = 0; mf < 4; mf++)
#pragma unroll
            for (int nf = 0; nf < 2; nf++) {
                f32x4 v = acc[mf][nf];
                int d = wn * 32 + nf * 16 + cl;
#pragma unroll
                for (int r = 0; r < 4; r++) {
                    int p = wm * 64 + mf * 16 + rl * 4 + r;
                    vpT[(size_t)bh * 8192 + d * 128 + p] = f2bf(v[r]);
                }
            }
        return;
    }

    // ---- K path: conv fold fused (kp never leaves the CU) ----
    __syncthreads();   // all staging reads done; smem reusable
    for (int i = tid; i < 640; i += 256) ef[i] = eff[i];

    const size_t obase = (size_t)bh * 40960;
    const int p2 = tid & 127;
    const int sub2 = (tid >> 7) * 16;

#pragma unroll
    for (int dh = 0; dh < 64; dh += 32) {
        __syncthreads();   // prior pass's kpad reads done (and ef visible on first pass)
        for (int i = tid; i < 256 * 36; i += 256) kpad[i] = 0.f;
        __syncthreads();
        if (wn == (dh >> 5)) {
#pragma unroll
            for (int mf = 0; mf < 4; mf++)
#pragma unroll
                for (int nf = 0; nf < 2; nf++) {
                    f32x4 v = acc[mf][nf];
                    int dcol = nf * 16 + cl;   // 0..31 within this half
#pragma unroll
                    for (int r = 0; r < 4; r++) {
                        int p = wm * 64 + mf * 16 + rl * 4 + r;
                        kpad[(64 + p) * 36 + dcol] = v[r];
                    }
                }
        }
        __syncthreads();

        float4 a5[5][4];
#pragma unroll
        for (int t = 0; t < 5; t++)
#pragma unroll
            for (int i = 0; i < 4; i++) a5[t][i] = make_float4(0.f, 0.f, 0.f, 0.f);

        for (int j = 0; j < 128; j++) {
            int rr = p2 + j + 1;
            float4 kv4[4];
#pragma unroll
            for (int i = 0; i < 4; i++) kv4[i] = *(const float4*)&kpad[rr * 36 + sub2 + i * 4];
            float wt[5];
#pragma unroll
            for (int t = 0; t < 5; t++) wt[t] = ef[t * 128 + j];
#pragma unroll
            for (int t = 0; t < 5; t++)
#pragma unroll
                for (int i = 0; i < 4; i++) {
                    a5[t][i].x = fmaf(wt[t], kv4[i].x, a5[t][i].x);
                    a5[t][i].y = fmaf(wt[t], kv4[i].y, a5[t][i].y);
                    a5[t][i].z = fmaf(wt[t], kv4[i].z, a5[t][i].z);
                    a5[t][i].w = fmaf(wt[t], kv4[i].w, a5[t][i].w);
                }
        }

#pragma unroll
        for (int t = 0; t < 5; t++)
#pragma unroll
            for (int i = 0; i < 4; i++) {
                int d0 = dh + sub2 + i * 4;
                ushort4 o;
                o.x = f2bf(a5[t][i].x * 0.125f);
                o.y = f2bf(a5[t][i].y * 0.125f);
                o.z = f2bf(a5[t][i].z * 0.125f);
                o.w = f2bf(a5[t][i].w * 0.125f);
                *(ushort4*)&keP[obase + (size_t)p2 * 320 + t * 64 + d0] = o;
            }
    }
}

// ---------------- fused attn: MFMA QK^T + in-register softmax + MFMA PV ----------------
// Structure frozen (R12 green); T5 setprio retained (neutral-to-positive, free).
__global__ __launch_bounds__(256) void attn_kernel(const u16* __restrict__ qg,
                                                   const u16* __restrict__ keP,
                                                   const u16* __restrict__ vpT,
                                                   u16* __restrict__ concat) {
    __shared__ __align__(16) char smem[32768];
    char* qswz = smem;              // [68 rows][8 slots of 16B], slot^=(row&7)
    char* keB = smem + 8704;        // [128 p][8 slots], slot^=(p&7)
    char* wlds = smem;              // phase2: [64 s][16 slots], slot^=(s&7)
    char* vps = smem + 16384;       // phase2: [64 d][16 slots], slot^=(d&7)

    int bh, st;
    xcd_decode(blockIdx.x, 32, bh, st);   // 128 bh-groups x 32 st-members (keP/vpT L2-resident per XCD)
    const int b = bh >> 3, h = bh & 7;
    const int s0 = st * 64;
    const int tid = threadIdx.x;
    const int w = tid >> 6, l = tid & 63;
    const int cl = l & 15, kg = l >> 4;   // 0..3

    // ---- stage qext rows s0-2 .. s0+65 (bounds-checked, reg->swizzled ds_write)
    const u16* qb = qg + (size_t)bh * SN * DEPTH;
    for (int i = tid; i < 68 * 8; i += 256) {
        int row = i >> 3, slot = i & 7;
        int srow = s0 + row - 2;
        int4 val = make_int4(0, 0, 0, 0);
        if (srow >= 0 && srow < SN)
            val = *(const int4*)(qb + (size_t)srow * 64 + slot * 8);
        *(int4*)(qswz + row * 128 + ((slot ^ (row & 7)) * 16)) = val;
    }

    f32x4 acc[8];
    const f32x4 z4 = {0.f, 0.f, 0.f, 0.f};
#pragma unroll
    for (int nf = 0; nf < 8; nf++) acc[nf] = z4;

    const char* kePb = (const char*)(keP + (size_t)bh * 40960);
    for (int kt = 0; kt < 5; kt++) {
        __syncthreads();
#pragma unroll
        for (int it = 0; it < 4; it++) {
            int i = it * 256 + tid;
            int p = i >> 3, slot = i & 7;
            const char* src = kePb + 2 * ((size_t)p * 320 + kt * 64) + ((slot ^ (p & 7)) * 16);
            __builtin_amdgcn_global_load_lds((const __attribute__((address_space(1))) void*)src,
                                             (__attribute__((address_space(3))) void*)(keB + i * 16),
                                             16, 0, 0);
        }
        __syncthreads();
        __builtin_amdgcn_s_setprio(1);
#pragma unroll
        for (int ks = 0; ks < 2; ks++) {
            int slot = ks * 4 + kg;
            int arow = w * 16 + kt + cl;   // shifted q row (t = kt fold)
            bf16x8 af = *(const bf16x8*)(qswz + arow * 128 + ((slot ^ (arow & 7)) * 16));
#pragma unroll
            for (int nf = 0; nf < 8; nf++) {
                int prow = nf * 16 + cl;
                bf16x8 bf = *(const bf16x8*)(keB + prow * 128 + ((slot ^ (prow & 7)) * 16));
                acc[nf] = __builtin_amdgcn_mfma_f32_16x16x32_bf16(af, bf, acc[nf], 0, 0, 0);
            }
        }
        __builtin_amdgcn_s_setprio(0);
    }
    __syncthreads();   // QK^T reads done; phase-1 LDS dead

    // issue vpT staging now -> flies under softmax (async global->LDS)
    const char* vpb = (const char*)(vpT + (size_t)bh * 8192);
#pragma unroll
    for (int it = 0; it < 4; it++) {
        int i = it * 256 + tid;
        int d = i >> 4, slot = i & 15;
        const char* src = vpb + 2 * ((size_t)d * 128) + ((slot ^ (d & 7)) * 16);
        __builtin_amdgcn_global_load_lds((const __attribute__((address_space(1))) void*)src,
                                         (__attribute__((address_space(3))) void*)(vps + i * 16),
                                         16, 0, 0);
    }

    // in-register softmax: lane holds rows kg*4+r (r=0..3), cols nf*16+cl
    float inv[4];
#pragma unroll
    for (int r = 0; r < 4; r++) {
        float m = acc[0][r];
#pragma unroll
        for (int nf = 1; nf < 8; nf++) m = fmaxf(m, acc[nf][r]);
        m = fmaxf(m, __shfl_xor(m, 1));
        m = fmaxf(m, __shfl_xor(m, 2));
        m = fmaxf(m, __shfl_xor(m, 4));
        m = fmaxf(m, __shfl_xor(m, 8));
        float s = 0.f;
#pragma unroll
        for (int nf = 0; nf < 8; nf++) {
            float e = __expf(acc[nf][r] - m);
            acc[nf][r] = e;
            s += e;
        }
        s += __shfl_xor(s, 1);
        s += __shfl_xor(s, 2);
        s += __shfl_xor(s, 4);
        s += __shfl_xor(s, 8);
        inv[r] = 1.0f / s;
    }
    // write W bf16 to swizzled wlds
#pragma unroll
    for (int r = 0; r < 4; r++) {
        int row = w * 16 + kg * 4 + r;
#pragma unroll
        for (int nf = 0; nf < 8; nf++) {
            int col = nf * 16 + cl;
            int slot = col >> 3, within = col & 7;
            *(u16*)(wlds + row * 256 + ((slot ^ (row & 7)) * 8 + within) * 2) = f2bf(acc[nf][r] * inv[r]);
        }
    }
    __syncthreads();   // drains vps vmcnt + wlds writes

    // PV: C[64 s][64 d] = W[64x128] @ VpT^T
    f32x4 acc2[4];
#pragma unroll
    for (int nf = 0; nf < 4; nf++) acc2[nf] = z4;
    __builtin_amdgcn_s_setprio(1);
#pragma unroll
    for (int ks = 0; ks < 4; ks++) {
        int slot = ks * 4 + kg;
        int arow = w * 16 + cl;
        bf16x8 af = *(const bf16x8*)(wlds + arow * 256 + ((slot ^ (arow & 7)) * 16));
#pragma unroll
        for (int nf = 0; nf < 4; nf++) {
            int drow = nf * 16 + cl;
            bf16x8 bf = *(const bf16x8*)(vps + drow * 256 + ((slot ^ (drow & 7)) * 16));
            acc2[nf] = __builtin_amdgcn_mfma_f32_16x16x32_bf16(af, bf, acc2[nf], 0, 0, 0);
        }
    }
    __builtin_amdgcn_s_setprio(0);
    // epilogue: concat bf16
#pragma unroll
    for (int nf = 0; nf < 4; nf++) {
#pragma unroll
        for (int r = 0; r < 4; r++) {
            int srow = s0 + w * 16 + kg * 4 + r;
            int d = nf * 16 + cl;
            concat[((size_t)b * SN + srow) * DM + h * 64 + d] = f2bf(acc2[nf][r]);
        }
    }
}

extern "C" void kernel_launch(void* const* d_in, const int* in_sizes, int n_in,
                              void* d_out, int out_size, void* d_ws, size_t ws_size,
                              hipStream_t stream) {
    const float* x = (const float*)d_in[0];
    const void* mask = d_in[1];
    const float* wq = (const float*)d_in[2];
    const float* wk = (const float*)d_in[3];
    const float* wv = (const float*)d_in[4];
    const float* e_w = (const float*)d_in[5];
    const float* f_w = (const float*)d_in[6];
    const float* ck1 = (const float*)d_in[7];
    // conv biases (d_in[8],[10],[12]) are uniform logit shifts -> softmax-invariant, dropped exactly
    const float* ck3 = (const float*)d_in[9];
    const float* ck5 = (const float*)d_in[11];
    const float* dw = (const float*)d_in[13];
    const float* db = (const float*)d_in[14];
    const int* table = (const int*)d_in[15];

    float* ws = (float*)d_ws;
    u16* qb = (u16*)(ws + OFF_QB);
    u16* G = (u16*)(ws + OFF_G);
    u16* cb = (u16*)(ws + OFF_CB);
    u16* xb = (u16*)(ws + OFF_XB);
    u16* wqT = (u16*)(ws + OFF_WQT);
    u16* wkT = (u16*)(ws + OFF_WKT);
    u16* wvT = (u16*)(ws + OFF_WVT);
    u16* dwT = (u16*)(ws + OFF_DWT);
    u16* vpT = (u16*)(ws + OFF_VPT);
    u16* keP = (u16*)(ws + OFF_KEP);
    float* eff = ws + OFF_EFF;
    int* counts = (int*)(ws + OFF_CNT);
    float* out = (float*)d_out;

    prep_kernel<<<dim3(17), dim3(256), 0, stream>>>(mask, counts, ck1, ck3, ck5, eff);
    convert_x_kernel<<<dim3(4096), dim3(256), 0, stream>>>(x, xb);
    convert_wT_kernel<<<dim3(16, 16, 4), dim3(256), 0, stream>>>(wq, wk, wv, dw, wqT, wkT, wvT, dwT);
    gemm_q<<<dim3(1024), dim3(256), 0, stream>>>(xb, wqT, qb);
    gather_kernel<<<dim3(128, 16), dim3(256), 0, stream>>>(xb, table, counts, e_w, f_w, G);
    proj_kernel<<<dim3(256), dim3(256), 0, stream>>>(G, wkT, wvT, eff, keP, vpT);
    attn_kernel<<<dim3(4096), dim3(256), 0, stream>>>(qb, keP, vpT, cb);
    gemm_out<<<dim3(1024), dim3(256), 0, stream>>>(cb, dwT, out, db);
}

// Round 17
// 209.212 us; speedup vs baseline: 1.0380x; 1.0380x over previous
//
#include <hip/hip_runtime.h>
#include <hip/hip_bf16.h>

#define BN 16
#define SN 2048
#define DM 512
#define HN 8
#define PN 128
#define DEPTH 64
#define CSZ 16

typedef unsigned short u16;
typedef __bf16 bf16x8 __attribute__((ext_vector_type(8)));
typedef float f32x4 __attribute__((ext_vector_type(4)));

// workspace layout (float-unit offsets)
#define OFF_QB   0ull          // Q bf16 (16.7M u16)
#define OFF_G    8388608ull    // G bf16: [(kv*8+h)*16+b][128 p][512] = 32768x512 u16
#define OFF_CB   25165824ull   // concat bf16
#define OFF_WQT  33554432ull   // 4x(512x512) u16 transposed (wq,wk,wv,dw)
#define OFF_WKT  33685504ull
#define OFF_WVT  33816576ull
#define OFF_DWT  33947648ull
#define OFF_KP   34078720ull   // f32 [bh][p][64]
#define OFF_VPT  35127296ull   // u16 [bh][d=64][p=128]
#define OFF_KEP  35651584ull   // u16 [bh][p=128][320]
#define OFF_EFF  38273024ull
#define OFF_CNT  38273664ull
#define OFF_XB   38273792ull   // x bf16 (16.7M u16)

__device__ __forceinline__ u16 f2bf(float f) {
    unsigned u = __float_as_uint(f);
    u = (u + 0x7fffu + ((u >> 16) & 1u)) >> 16;   // RNE
    return (u16)u;
}
__device__ __forceinline__ float b2f(u16 h) {
    return __uint_as_float(((unsigned)h) << 16);
}

// chunked XCD swizzle: consecutive dispatch ids round-robin the 8 XCDs.
__device__ __forceinline__ void xcd_decode(int bid, int nmem, int& g, int& j) {
    int xcd = bid & 7;
    int t = bid >> 3;
    j = t % nmem;
    g = (t / nmem) * 8 + xcd;
}

// ---------------- merged prologue: convert_x | wT transpose | counts | eff ----------------
// blocks 0..4095: x f32->bf16 (16 floats/thread); 4096..5119: weight transpose (4x 16x16);
// 5120..5135: mask counts; 5136: eff conv combine. All independent writes.
__global__ __launch_bounds__(256) void prologue_kernel(const float* __restrict__ x, u16* __restrict__ xb,
                                                       const float* w0, const float* w1, const float* w2, const float* w3,
                                                       u16* o0, u16* o1, u16* o2, u16* o3,
                                                       const void* mask, int* counts,
                                                       const float* ck1, const float* ck3, const float* ck5, float* eff) {
    __shared__ float t[32][33];
    __shared__ int red[256];
    const int bid = blockIdx.x;
    const int tid = threadIdx.x;

    if (bid < 4096) {
        size_t i = ((size_t)bid * 256 + tid) * 16;
#pragma unroll
        for (int k = 0; k < 4; k++) {
            float4 v = *(const float4*)&x[i + k * 4];
            ushort4 o;
            o.x = f2bf(v.x); o.y = f2bf(v.y); o.z = f2bf(v.z); o.w = f2bf(v.w);
            *(ushort4*)&xb[i + k * 4] = o;
        }
        return;
    }
    if (bid < 5120) {
        int idx = bid - 4096;
        int z = idx >> 8, rem = idx & 255;
        int k0 = (rem >> 4) * 32, n0 = (rem & 15) * 32;
        const float* W = (z == 0) ? w0 : (z == 1) ? w1 : (z == 2) ? w2 : w3;
        u16* O = (z == 0) ? o0 : (z == 1) ? o1 : (z == 2) ? o2 : o3;
        int lx = tid & 31, ly = tid >> 5;  // 32 x 8
#pragma unroll
        for (int i = 0; i < 4; i++) t[ly + i * 8][lx] = W[(size_t)(k0 + ly + i * 8) * 512 + n0 + lx];
        __syncthreads();
#pragma unroll
        for (int i = 0; i < 4; i++) O[(size_t)(n0 + ly + i * 8) * 512 + k0 + lx] = f2bf(t[lx][ly + i * 8]);
        return;
    }
    if (bid == 5136) {
        for (int i = tid; i < 640; i += 256) {
            int tt = i >> 7, j = i & 127;
            float v = ck5[tt * 128 + j];
            if (tt >= 1 && tt <= 3) v += ck3[(tt - 1) * 128 + j];
            if (tt == 2) v += ck1[j];
            eff[i] = v * (1.0f / 3.0f);
        }
        return;
    }
    // counts: bid in [5120, 5136)
    int b = bid - 5120;
    const unsigned char* mb = (const unsigned char*)mask;
    bool is_byte = (mb[1] != 0);  // byte1 nonzero iff 1-byte bool storage (len>=1024)
    int local = 0;
    if (is_byte) {
        const unsigned char* row = mb + (size_t)b * SN;
        for (int s = tid; s < SN; s += 256) local += (row[s] != 0);
    } else {
        const int* row = (const int*)mask + (size_t)b * SN;
        for (int s = tid; s < SN; s += 256) local += (row[s] != 0);
    }
    red[tid] = local;
    __syncthreads();
    for (int st = 128; st > 0; st >>= 1) {
        if (tid < st) red[tid] += red[tid + st];
        __syncthreads();
    }
    if (tid == 0) {
        int c = red[0];
        if (c < 1) c = 1;
        if (c > SN) c = SN;
        counts[b] = c;
    }
}

// ---------------- Q GEMM: xb(32768x512)bf16 @ wqT -> Q bf16 (B,H,S,depth) scatter ----------------
__global__ __launch_bounds__(256) void gemm_q(const u16* __restrict__ A,
                                              const u16* __restrict__ WT,
                                              u16* __restrict__ Q) {
    __shared__ __align__(16) char smem[32768];
    char* AsB = smem;
    char* BsB = smem + 16384;

    int g, j;
    xcd_decode(blockIdx.x, 4, g, j);   // 256 m-groups x 4 n-members
    const int m0 = g * 128, n0 = j * 128;
    const int tid = threadIdx.x;
    const int w = tid >> 6, l = tid & 63;
    const int wm = w >> 1, wn = w & 1;
    const int lr = l >> 3, sp = l & 7;
    const int slog = sp ^ lr;
    const int cl = l & 15, kg = l >> 4;

    const char* Ab = (const char*)A;
    const char* Bb = (const char*)WT;

    f32x4 acc[4][4];
    const f32x4 z4 = {0.f, 0.f, 0.f, 0.f};
#pragma unroll
    for (int mf = 0; mf < 4; mf++)
#pragma unroll
        for (int nf = 0; nf < 4; nf++) acc[mf][nf] = z4;

    for (int kt = 0; kt < 8; kt++) {
        __syncthreads();
#pragma unroll
        for (int i = 0; i < 4; i++) {
            int c = w * 4 + i;
            const char* ga = Ab + (size_t)(m0 + c * 8 + lr) * 1024 + kt * 128 + slog * 16;
            __builtin_amdgcn_global_load_lds((const __attribute__((address_space(1))) void*)ga,
                                             (__attribute__((address_space(3))) void*)(AsB + c * 1024),
                                             16, 0, 0);
            const char* gb = Bb + (size_t)(n0 + c * 8 + lr) * 1024 + kt * 128 + slog * 16;
            __builtin_amdgcn_global_load_lds((const __attribute__((address_space(1))) void*)gb,
                                             (__attribute__((address_space(3))) void*)(BsB + c * 1024),
                                             16, 0, 0);
        }
        __syncthreads();
#pragma unroll
        for (int ks = 0; ks < 2; ks++) {
            bf16x8 a[4], b[4];
#pragma unroll
            for (int mf = 0; mf < 4; mf++) {
                int row = wm * 64 + mf * 16 + cl;
                a[mf] = *(const bf16x8*)(AsB + row * 128 + (((ks * 4 + kg) ^ (row & 7)) * 16));
            }
#pragma unroll
            for (int nf = 0; nf < 4; nf++) {
                int row = wn * 64 + nf * 16 + cl;
                b[nf] = *(const bf16x8*)(BsB + row * 128 + (((ks * 4 + kg) ^ (row & 7)) * 16));
            }
#pragma unroll
            for (int mf = 0; mf < 4; mf++)
#pragma unroll
                for (int nf = 0; nf < 4; nf++)
                    acc[mf][nf] = __builtin_amdgcn_mfma_f32_16x16x32_bf16(a[mf], b[nf], acc[mf][nf], 0, 0, 0);
        }
    }

    const int rl = l >> 4;
#pragma unroll
    for (int mf = 0; mf < 4; mf++)
#pragma unroll
        for (int nf = 0; nf < 4; nf++) {
            f32x4 v = acc[mf][nf];
            int n = n0 + wn * 64 + nf * 16 + cl;
            int h = n >> 6, d = n & 63;
#pragma unroll
            for (int r = 0; r < 4; r++) {
                int m = m0 + wm * 64 + mf * 16 + rl * 4 + r;
                int b = m >> 11, s = m & 2047;
                Q[(size_t)((b * HN + h) * SN + s) * DEPTH + d] = f2bf(v[r]);
            }
        }
}

// ---------------- output projection GEMM: cb(32768x512)bf16 @ dwT + bias -> f32 ----------------
__global__ __launch_bounds__(256) void gemm_out(const u16* __restrict__ A,
                                                const u16* __restrict__ WT,
                                                float* __restrict__ O,
                                                const float* __restrict__ bias) {
    __shared__ __align__(16) char smem[32768];
    char* AsB = smem;
    char* BsB = smem + 16384;

    int g, j;
    xcd_decode(blockIdx.x, 4, g, j);   // 256 m-groups x 4 n-members
    const int m0 = g * 128, n0 = j * 128;
    const int tid = threadIdx.x;
    const int w = tid >> 6, l = tid & 63;
    const int wm = w >> 1, wn = w & 1;
    const int lr = l >> 3, sp = l & 7;
    const int slog = sp ^ lr;
    const int cl = l & 15, kg = l >> 4;

    const char* Ab = (const char*)A;
    const char* Bb = (const char*)WT;

    f32x4 acc[4][4];
    const f32x4 z4 = {0.f, 0.f, 0.f, 0.f};
#pragma unroll
    for (int mf = 0; mf < 4; mf++)
#pragma unroll
        for (int nf = 0; nf < 4; nf++) acc[mf][nf] = z4;

    for (int kt = 0; kt < 8; kt++) {
        __syncthreads();
#pragma unroll
        for (int i = 0; i < 4; i++) {
            int c = w * 4 + i;
            const char* ga = Ab + (size_t)(m0 + c * 8 + lr) * 1024 + kt * 128 + slog * 16;
            __builtin_amdgcn_global_load_lds((const __attribute__((address_space(1))) void*)ga,
                                             (__attribute__((address_space(3))) void*)(AsB + c * 1024),
                                             16, 0, 0);
            const char* gb = Bb + (size_t)(n0 + c * 8 + lr) * 1024 + kt * 128 + slog * 16;
            __builtin_amdgcn_global_load_lds((const __attribute__((address_space(1))) void*)gb,
                                             (__attribute__((address_space(3))) void*)(BsB + c * 1024),
                                             16, 0, 0);
        }
        __syncthreads();
#pragma unroll
        for (int ks = 0; ks < 2; ks++) {
            bf16x8 a[4], b[4];
#pragma unroll
            for (int mf = 0; mf < 4; mf++) {
                int row = wm * 64 + mf * 16 + cl;
                a[mf] = *(const bf16x8*)(AsB + row * 128 + (((ks * 4 + kg) ^ (row & 7)) * 16));
            }
#pragma unroll
            for (int nf = 0; nf < 4; nf++) {
                int row = wn * 64 + nf * 16 + cl;
                b[nf] = *(const bf16x8*)(BsB + row * 128 + (((ks * 4 + kg) ^ (row & 7)) * 16));
            }
#pragma unroll
            for (int mf = 0; mf < 4; mf++)
#pragma unroll
                for (int nf = 0; nf < 4; nf++)
                    acc[mf][nf] = __builtin_amdgcn_mfma_f32_16x16x32_bf16(a[mf], b[nf], acc[mf][nf], 0, 0, 0);
        }
    }

    const int rl = l >> 4;
#pragma unroll
    for (int mf = 0; mf < 4; mf++)
#pragma unroll
        for (int nf = 0; nf < 4; nf++) {
            f32x4 v = acc[mf][nf];
            int n = n0 + wn * 64 + nf * 16 + cl;
            float bs = bias[n];
#pragma unroll
            for (int r = 0; r < 4; r++) {
                int m = m0 + wm * 64 + mf * 16 + rl * 4 + r;
                O[(size_t)m * 512 + n] = v[r] + bs;
            }
        }
}

// ---------------- gather+combine: G[(kv*8+h)*16+b][p][dm] = bf16(Sum_c w[h][p][c] * xb[b][pos][dm]) ----------------
__global__ __launch_bounds__(256) void gather_kernel(const u16* __restrict__ xb,
                                                     const int* __restrict__ table, const int* __restrict__ counts,
                                                     const float* __restrict__ e_w, const float* __restrict__ f_w,
                                                     u16* __restrict__ G) {
    int p = blockIdx.x;   // 0..127
    int b = blockIdx.y;   // 0..15
    int tid = threadIdx.x;
    __shared__ int poss[16];
    __shared__ float ew_s[8][16], fw_s[8][16];
    if (tid < 16) {
        int R = counts[b];
        poss[tid] = table[(size_t)(R - 1) * PN * CSZ + p * CSZ + tid];
    }
    {
        int t2 = tid & 127;
        int h = t2 >> 4, c = t2 & 15;
        float v = ((tid < 128) ? e_w : f_w)[(size_t)(h * PN + p) * CSZ + c];
        if (tid < 128) ew_s[h][c] = v; else fw_s[h][c] = v;
    }
    __syncthreads();

    const u16* xrow = xb + (size_t)b * SN * 512;
#pragma unroll
    for (int half = 0; half < 2; half++) {
        int dm = half * 256 + tid;
        float ak[8] = {0.f, 0.f, 0.f, 0.f, 0.f, 0.f, 0.f, 0.f};
        float av[8] = {0.f, 0.f, 0.f, 0.f, 0.f, 0.f, 0.f, 0.f};
#pragma unroll
        for (int c = 0; c < 16; c++) {
            int pos = poss[c];
            if (pos < SN) {
                float xv = b2f(xrow[(size_t)pos * 512 + dm]);
#pragma unroll
                for (int h = 0; h < 8; h++) {
                    ak[h] = fmaf(ew_s[h][c], xv, ak[h]);
                    av[h] = fmaf(fw_s[h][c], xv, av[h]);
                }
            }
        }
#pragma unroll
        for (int h = 0; h < 8; h++) {
            G[((size_t)(h * 16 + b) * 128 + p) * 512 + dm] = f2bf(ak[h]);
            G[((size_t)((8 + h) * 16 + b) * 128 + p) * 512 + dm] = f2bf(av[h]);
        }
    }
}

// ---------------- proj: per (kv,h,b) tile G[128x512] @ w{k,v}T[h-slice 64x512] ----------------
__global__ __launch_bounds__(256) void proj_kernel(const u16* __restrict__ G,
                                                   const u16* __restrict__ wkT, const u16* __restrict__ wvT,
                                                   float* __restrict__ kp, u16* __restrict__ vpT) {
    __shared__ __align__(16) char smem[24576];
    char* AsB = smem;           // 128 rows x 64k bf16 = 16KB
    char* BsB = smem + 16384;   // 64 rows x 64k bf16 = 8KB

    const int mt = blockIdx.x;          // 0..255 = kv*128 + h*16 + b
    const int kv = mt >> 7, h = (mt >> 4) & 7, bb = mt & 15;
    const int tid = threadIdx.x;
    const int w = tid >> 6, l = tid & 63;
    const int wm = w >> 1, wn = w & 1;
    const int lr = l >> 3, sp = l & 7;
    const int slog = sp ^ lr;
    const int cl = l & 15, kg = l >> 4;

    const char* Ab = (const char*)(G + (size_t)mt * 65536);
    const char* Bb = (const char*)((kv ? wvT : wkT) + (size_t)h * 64 * 512);

    f32x4 acc[4][2];
    const f32x4 z4 = {0.f, 0.f, 0.f, 0.f};
#pragma unroll
    for (int mf = 0; mf < 4; mf++)
#pragma unroll
        for (int nf = 0; nf < 2; nf++) acc[mf][nf] = z4;

    for (int kt = 0; kt < 8; kt++) {
        __syncthreads();
#pragma unroll
        for (int i = 0; i < 4; i++) {
            int c = w * 4 + i;
            const char* ga = Ab + (size_t)(c * 8 + lr) * 1024 + kt * 128 + slog * 16;
            __builtin_amdgcn_global_load_lds((const __attribute__((address_space(1))) void*)ga,
                                             (__attribute__((address_space(3))) void*)(AsB + c * 1024),
                                             16, 0, 0);
        }
#pragma unroll
        for (int i = 0; i < 2; i++) {
            int c = w * 2 + i;
            const char* gb = Bb + (size_t)(c * 8 + lr) * 1024 + kt * 128 + slog * 16;
            __builtin_amdgcn_global_load_lds((const __attribute__((address_space(1))) void*)gb,
                                             (__attribute__((address_space(3))) void*)(BsB + c * 1024),
                                             16, 0, 0);
        }
        __syncthreads();
#pragma unroll
        for (int ks = 0; ks < 2; ks++) {
            bf16x8 a[4], b[2];
#pragma unroll
            for (int mf = 0; mf < 4; mf++) {
                int row = wm * 64 + mf * 16 + cl;
                a[mf] = *(const bf16x8*)(AsB + row * 128 + (((ks * 4 + kg) ^ (row & 7)) * 16));
            }
#pragma unroll
            for (int nf = 0; nf < 2; nf++) {
                int row = wn * 32 + nf * 16 + cl;
                b[nf] = *(const bf16x8*)(BsB + row * 128 + (((ks * 4 + kg) ^ (row & 7)) * 16));
            }
#pragma unroll
            for (int mf = 0; mf < 4; mf++)
#pragma unroll
                for (int nf = 0; nf < 2; nf++)
                    acc[mf][nf] = __builtin_amdgcn_mfma_f32_16x16x32_bf16(a[mf], b[nf], acc[mf][nf], 0, 0, 0);
        }
    }

    const int rl = l >> 4;
    const int bh = bb * HN + h;
#pragma unroll
    for (int mf = 0; mf < 4; mf++)
#pragma unroll
        for (int nf = 0; nf < 2; nf++) {
            f32x4 v = acc[mf][nf];
            int d = wn * 32 + nf * 16 + cl;
#pragma unroll
            for (int r = 0; r < 4; r++) {
                int p = wm * 64 + mf * 16 + rl * 4 + r;
                if (kv == 0)
                    kp[((size_t)bh * PN + p) * DEPTH + d] = v[r];
                else
                    vpT[(size_t)bh * 8192 + d * 128 + p] = f2bf(v[r]);
            }
        }
}

// ---------------- fold conv into K side: keP[bh][p][t*64+d] bf16 (p-major, 1/8 folded) ----------------
__global__ __launch_bounds__(256) void ke_kernel(const float* __restrict__ kproj,
                                                 const float* __restrict__ eff,
                                                 u16* __restrict__ keP) {
    int blk = blockIdx.x;
    int bh = blk >> 1;
    int dh = (blk & 1) * 32;
    int tid = threadIdx.x;
    int p = tid & 127;
    int sub = (tid >> 7) * 16;

    __shared__ float kpad[256 * 48];
    __shared__ float ef[640];

    for (int i = tid; i < 256 * 48; i += 256) kpad[i] = 0.f;
    for (int i = tid; i < 640; i += 256) ef[i] = eff[i];
    __syncthreads();
    for (int i = tid; i < 128 * 8; i += 256) {
        int row = i >> 3, c4 = (i & 7) * 4;
        float4 v = *(const float4*)&kproj[(size_t)bh * 8192 + row * 64 + dh + c4];
        *(float4*)&kpad[(64 + row) * 48 + c4] = v;
    }
    __syncthreads();

    float4 acc[5][4];
#pragma unroll
    for (int t = 0; t < 5; t++)
#pragma unroll
        for (int i = 0; i < 4; i++) acc[t][i] = make_float4(0.f, 0.f, 0.f, 0.f);

    for (int j = 0; j < 128; j++) {
        int rr = p + j + 1;
        float4 kv[4];
#pragma unroll
        for (int i = 0; i < 4; i++) kv[i] = *(const float4*)&kpad[rr * 48 + sub + i * 4];
        float w[5];
#pragma unroll
        for (int t = 0; t < 5; t++) w[t] = ef[t * 128 + j];
#pragma unroll
        for (int t = 0; t < 5; t++)
#pragma unroll
            for (int i = 0; i < 4; i++) {
                acc[t][i].x = fmaf(w[t], kv[i].x, acc[t][i].x);
                acc[t][i].y = fmaf(w[t], kv[i].y, acc[t][i].y);
                acc[t][i].z = fmaf(w[t], kv[i].z, acc[t][i].z);
                acc[t][i].w = fmaf(w[t], kv[i].w, acc[t][i].w);
            }
    }

    size_t obase = (size_t)bh * 40960 + (size_t)p * 320;
#pragma unroll
    for (int t = 0; t < 5; t++)
#pragma unroll
        for (int i = 0; i < 4; i++) {
            int d0 = dh + sub + i * 4;
            ushort4 o;
            o.x = f2bf(acc[t][i].x * 0.125f);
            o.y = f2bf(acc[t][i].y * 0.125f);
            o.z = f2bf(acc[t][i].z * 0.125f);
            o.w = f2bf(acc[t][i].w * 0.125f);
            *(ushort4*)&keP[obase + t * 64 + d0] = o;
        }
}

// ---------------- fused attn: MFMA QK^T + in-register softmax + MFMA PV ----------------
// Structure frozen (R12 green); T5 setprio retained (neutral-to-positive, free).
__global__ __launch_bounds__(256) void attn_kernel(const u16* __restrict__ qg,
                                                   const u16* __restrict__ keP,
                                                   const u16* __restrict__ vpT,
                                                   u16* __restrict__ concat) {
    __shared__ __align__(16) char smem[32768];
    char* qswz = smem;              // [68 rows][8 slots of 16B], slot^=(row&7)
    char* keB = smem + 8704;        // [128 p][8 slots], slot^=(p&7)
    char* wlds = smem;              // phase2: [64 s][16 slots], slot^=(s&7)
    char* vps = smem + 16384;       // phase2: [64 d][16 slots], slot^=(d&7)

    int bh, st;
    xcd_decode(blockIdx.x, 32, bh, st);   // 128 bh-groups x 32 st-members (keP/vpT L2-resident per XCD)
    const int b = bh >> 3, h = bh & 7;
    const int s0 = st * 64;
    const int tid = threadIdx.x;
    const int w = tid >> 6, l = tid & 63;
    const int cl = l & 15, kg = l >> 4;   // 0..3

    // ---- stage qext rows s0-2 .. s0+65 (bounds-checked, reg->swizzled ds_write)
    const u16* qb = qg + (size_t)bh * SN * DEPTH;
    for (int i = tid; i < 68 * 8; i += 256) {
        int row = i >> 3, slot = i & 7;
        int srow = s0 + row - 2;
        int4 val = make_int4(0, 0, 0, 0);
        if (srow >= 0 && srow < SN)
            val = *(const int4*)(qb + (size_t)srow * 64 + slot * 8);
        *(int4*)(qswz + row * 128 + ((slot ^ (row & 7)) * 16)) = val;
    }

    f32x4 acc[8];
    const f32x4 z4 = {0.f, 0.f, 0.f, 0.f};
#pragma unroll
    for (int nf = 0; nf < 8; nf++) acc[nf] = z4;

    const char* kePb = (const char*)(keP + (size_t)bh * 40960);
    for (int kt = 0; kt < 5; kt++) {
        __syncthreads();
#pragma unroll
        for (int it = 0; it < 4; it++) {
            int i = it * 256 + tid;
            int p = i >> 3, slot = i & 7;
            const char* src = kePb + 2 * ((size_t)p * 320 + kt * 64) + ((slot ^ (p & 7)) * 16);
            __builtin_amdgcn_global_load_lds((const __attribute__((address_space(1))) void*)src,
                                             (__attribute__((address_space(3))) void*)(keB + i * 16),
                                             16, 0, 0);
        }
        __syncthreads();
        __builtin_amdgcn_s_setprio(1);
#pragma unroll
        for (int ks = 0; ks < 2; ks++) {
            int slot = ks * 4 + kg;
            int arow = w * 16 + kt + cl;   // shifted q row (t = kt fold)
            bf16x8 af = *(const bf16x8*)(qswz + arow * 128 + ((slot ^ (arow & 7)) * 16));
#pragma unroll
            for (int nf = 0; nf < 8; nf++) {
                int prow = nf * 16 + cl;
                bf16x8 bf = *(const bf16x8*)(keB + prow * 128 + ((slot ^ (prow & 7)) * 16));
                acc[nf] = __builtin_amdgcn_mfma_f32_16x16x32_bf16(af, bf, acc[nf], 0, 0, 0);
            }
        }
        __builtin_amdgcn_s_setprio(0);
    }
    __syncthreads();   // QK^T reads done; phase-1 LDS dead

    // issue vpT staging now -> flies under softmax (async global->LDS)
    const char* vpb = (const char*)(vpT + (size_t)bh * 8192);
#pragma unroll
    for (int it = 0; it < 4; it++) {
        int i = it * 256 + tid;
        int d = i >> 4, slot = i & 15;
        const char* src = vpb + 2 * ((size_t)d * 128) + ((slot ^ (d & 7)) * 16);
        __builtin_amdgcn_global_load_lds((const __attribute__((address_space(1))) void*)src,
                                         (__attribute__((address_space(3))) void*)(vps + i * 16),
                                         16, 0, 0);
    }

    // in-register softmax: lane holds rows kg*4+r (r=0..3), cols nf*16+cl
    float inv[4];
#pragma unroll
    for (int r = 0; r < 4; r++) {
        float m = acc[0][r];
#pragma unroll
        for (int nf = 1; nf < 8; nf++) m = fmaxf(m, acc[nf][r]);
        m = fmaxf(m, __shfl_xor(m, 1));
        m = fmaxf(m, __shfl_xor(m, 2));
        m = fmaxf(m, __shfl_xor(m, 4));
        m = fmaxf(m, __shfl_xor(m, 8));
        float s = 0.f;
#pragma unroll
        for (int nf = 0; nf < 8; nf++) {
            float e = __expf(acc[nf][r] - m);
            acc[nf][r] = e;
            s += e;
        }
        s += __shfl_xor(s, 1);
        s += __shfl_xor(s, 2);
        s += __shfl_xor(s, 4);
        s += __shfl_xor(s, 8);
        inv[r] = 1.0f / s;
    }
    // write W bf16 to swizzled wlds
#pragma unroll
    for (int r = 0; r < 4; r++) {
        int row = w * 16 + kg * 4 + r;
#pragma unroll
        for (int nf = 0; nf < 8; nf++) {
            int col = nf * 16 + cl;
            int slot = col >> 3, within = col & 7;
            *(u16*)(wlds + row * 256 + ((slot ^ (row & 7)) * 8 + within) * 2) = f2bf(acc[nf][r] * inv[r]);
        }
    }
    __syncthreads();   // drains vps vmcnt + wlds writes

    // PV: C[64 s][64 d] = W[64x128] @ VpT^T
    f32x4 acc2[4];
#pragma unroll
    for (int nf = 0; nf < 4; nf++) acc2[nf] = z4;
    __builtin_amdgcn_s_setprio(1);
#pragma unroll
    for (int ks = 0; ks < 4; ks++) {
        int slot = ks * 4 + kg;
        int arow = w * 16 + cl;
        bf16x8 af = *(const bf16x8*)(wlds + arow * 256 + ((slot ^ (arow & 7)) * 16));
#pragma unroll
        for (int nf = 0; nf < 4; nf++) {
            int drow = nf * 16 + cl;
            bf16x8 bf = *(const bf16x8*)(vps + drow * 256 + ((slot ^ (drow & 7)) * 16));
            acc2[nf] = __builtin_amdgcn_mfma_f32_16x16x32_bf16(af, bf, acc2[nf], 0, 0, 0);
        }
    }
    __builtin_amdgcn_s_setprio(0);
    // epilogue: concat bf16
#pragma unroll
    for (int nf = 0; nf < 4; nf++) {
#pragma unroll
        for (int r = 0; r < 4; r++) {
            int srow = s0 + w * 16 + kg * 4 + r;
            int d = nf * 16 + cl;
            concat[((size_t)b * SN + srow) * DM + h * 64 + d] = f2bf(acc2[nf][r]);
        }
    }
}

extern "C" void kernel_launch(void* const* d_in, const int* in_sizes, int n_in,
                              void* d_out, int out_size, void* d_ws, size_t ws_size,
                              hipStream_t stream) {
    const float* x = (const float*)d_in[0];
    const void* mask = d_in[1];
    const float* wq = (const float*)d_in[2];
    const float* wk = (const float*)d_in[3];
    const float* wv = (const float*)d_in[4];
    const float* e_w = (const float*)d_in[5];
    const float* f_w = (const float*)d_in[6];
    const float* ck1 = (const float*)d_in[7];
    // conv biases (d_in[8],[10],[12]) are uniform logit shifts -> softmax-invariant, dropped exactly
    const float* ck3 = (const float*)d_in[9];
    const float* ck5 = (const float*)d_in[11];
    const float* dw = (const float*)d_in[13];
    const float* db = (const float*)d_in[14];
    const int* table = (const int*)d_in[15];

    float* ws = (float*)d_ws;
    u16* qb = (u16*)(ws + OFF_QB);
    u16* G = (u16*)(ws + OFF_G);
    u16* cb = (u16*)(ws + OFF_CB);
    u16* xb = (u16*)(ws + OFF_XB);
    u16* wqT = (u16*)(ws + OFF_WQT);
    u16* wkT = (u16*)(ws + OFF_WKT);
    u16* wvT = (u16*)(ws + OFF_WVT);
    u16* dwT = (u16*)(ws + OFF_DWT);
    float* kp = ws + OFF_KP;
    u16* vpT = (u16*)(ws + OFF_VPT);
    u16* keP = (u16*)(ws + OFF_KEP);
    float* eff = ws + OFF_EFF;
    int* counts = (int*)(ws + OFF_CNT);
    float* out = (float*)d_out;

    prologue_kernel<<<dim3(5137), dim3(256), 0, stream>>>(x, xb, wq, wk, wv, dw, wqT, wkT, wvT, dwT,
                                                          mask, counts, ck1, ck3, ck5, eff);
    gemm_q<<<dim3(1024), dim3(256), 0, stream>>>(xb, wqT, qb);
    gather_kernel<<<dim3(128, 16), dim3(256), 0, stream>>>(xb, table, counts, e_w, f_w, G);
    proj_kernel<<<dim3(256), dim3(256), 0, stream>>>(G, wkT, wvT, kp, vpT);
    ke_kernel<<<dim3(256), dim3(256), 0, stream>>>(kp, eff, keP);
    attn_kernel<<<dim3(4096), dim3(256), 0, stream>>>(qb, keP, vpT, cb);
    gemm_out<<<dim3(1024), dim3(256), 0, stream>>>(cb, dwT, out, db);
}